// Round 1
// baseline (59.450 us; speedup 1.0000x reference)
//
#include <hip/hip_runtime.h>
#include <math.h>

// Hausdorff distance between X[8192,3] and Y[8192,3] (float32).
// d2min_A[i] = min_j ||A_i - B_j||^2 ; answer = sqrt(max over all 16384 mins).

constexpr int NPTS = 8192;
constexpr int THREADS = 256;
constexpr int R = 4;                             // rows per thread
constexpr int ROWS_PER_BLOCK = THREADS * R;      // 1024
constexpr int RG = NPTS / ROWS_PER_BLOCK;        // 8 row-groups
constexpr int SEG_J = 512;                       // B points per segment
constexpr int SEGS = NPTS / SEG_J;               // 16 segments
constexpr int BLOCKS_PER_DIR = RG * SEGS;        // 128

__global__ void init_min_kernel(unsigned* wsmin, int n) {
    int i = blockIdx.x * blockDim.x + threadIdx.x;
    if (i < n) wsmin[i] = 0x7F800000u;  // +inf bits
}

__global__ __launch_bounds__(THREADS) void pair_min_kernel(
        const float* __restrict__ X, const float* __restrict__ Y,
        unsigned* __restrict__ minXY, unsigned* __restrict__ minYX) {
    int b   = blockIdx.x;
    int dir = b / BLOCKS_PER_DIR;          // 0: X->Y, 1: Y->X
    int rem = b - dir * BLOCKS_PER_DIR;
    int rg  = rem / SEGS;
    int seg = rem - rg * SEGS;

    const float* A   = dir ? Y : X;
    const float* B   = dir ? X : Y;
    unsigned* omin   = dir ? minYX : minXY;

    __shared__ float Bs[SEG_J * 3];
    int t = threadIdx.x;

    // Stage B segment into LDS (contiguous 6 KB, coalesced)
    const float* Bseg = B + seg * SEG_J * 3;
    for (int i = t; i < SEG_J * 3; i += THREADS) Bs[i] = Bseg[i];

    // Load this thread's 4 A-rows into registers
    int r0 = rg * ROWS_PER_BLOCK + t;
    float ax[R], ay[R], az[R], m[R];
#pragma unroll
    for (int r = 0; r < R; ++r) {
        int row = r0 + r * THREADS;
        ax[r] = A[row * 3 + 0];
        ay[r] = A[row * 3 + 1];
        az[r] = A[row * 3 + 2];
        m[r]  = __builtin_inff();
    }
    __syncthreads();

#pragma unroll 2
    for (int j = 0; j < SEG_J; ++j) {
        float bx = Bs[3 * j + 0];   // wave-uniform address -> LDS broadcast
        float by = Bs[3 * j + 1];
        float bz = Bs[3 * j + 2];
#pragma unroll
        for (int r = 0; r < R; ++r) {
            float dx = ax[r] - bx;
            float dy = ay[r] - by;
            float dz = az[r] - bz;
            float d2 = fmaf(dx, dx, fmaf(dy, dy, dz * dz));
            m[r] = fminf(m[r], d2);
        }
    }

#pragma unroll
    for (int r = 0; r < R; ++r) {
        // non-negative float bits order like unsigned -> uint atomicMin is exact
        atomicMin(&omin[r0 + r * THREADS], __float_as_uint(m[r]));
    }
}

__global__ __launch_bounds__(THREADS) void finalize_kernel(
        const unsigned* __restrict__ wsmin, float* __restrict__ out, int n) {
    int t = threadIdx.x;
    float mx = 0.f;
    for (int i = t; i < n; i += THREADS) mx = fmaxf(mx, __uint_as_float(wsmin[i]));
    for (int o = 32; o > 0; o >>= 1) mx = fmaxf(mx, __shfl_down(mx, o));
    __shared__ float wmax[THREADS / 64];
    if ((t & 63) == 0) wmax[t >> 6] = mx;
    __syncthreads();
    if (t == 0) {
        float mm = wmax[0];
        for (int w = 1; w < THREADS / 64; ++w) mm = fmaxf(mm, wmax[w]);
        out[0] = sqrtf(mm);
    }
}

// ---------- fallback path (uses only d_out as scratch) ----------

__global__ void init_scalar_kernel(unsigned* o) {
    if (blockIdx.x == 0 && threadIdx.x == 0) o[0] = 0u;  // 0.0f
}

__global__ __launch_bounds__(THREADS) void hausdorff_simple_kernel(
        const float* __restrict__ X, const float* __restrict__ Y,
        unsigned* __restrict__ omax) {
    int b = blockIdx.x;
    int dir = (b >= (NPTS / THREADS)) ? 1 : 0;
    int rem = b - dir * (NPTS / THREADS);
    const float* A = dir ? Y : X;
    const float* B = dir ? X : Y;

    int row = rem * THREADS + threadIdx.x;
    float ax = A[row * 3 + 0], ay = A[row * 3 + 1], az = A[row * 3 + 2];
    float m = __builtin_inff();

    __shared__ float Bs[SEG_J * 3];
    for (int seg = 0; seg < SEGS; ++seg) {
        __syncthreads();
        const float* Bseg = B + seg * SEG_J * 3;
        for (int i = threadIdx.x; i < SEG_J * 3; i += THREADS) Bs[i] = Bseg[i];
        __syncthreads();
#pragma unroll 4
        for (int j = 0; j < SEG_J; ++j) {
            float dx = ax - Bs[3 * j + 0];
            float dy = ay - Bs[3 * j + 1];
            float dz = az - Bs[3 * j + 2];
            m = fminf(m, fmaf(dx, dx, fmaf(dy, dy, dz * dz)));
        }
    }
    for (int o = 32; o > 0; o >>= 1) m = fmaxf(m, __shfl_down(m, o));
    __shared__ float wmax[THREADS / 64];
    if ((threadIdx.x & 63) == 0) wmax[threadIdx.x >> 6] = m;
    __syncthreads();
    if (threadIdx.x == 0) {
        float mm = fmaxf(fmaxf(wmax[0], wmax[1]), fmaxf(wmax[2], wmax[3]));
        atomicMax(omax, __float_as_uint(mm));
    }
}

__global__ void sqrt_inplace_kernel(float* out) {
    if (blockIdx.x == 0 && threadIdx.x == 0) out[0] = sqrtf(out[0]);
}

extern "C" void kernel_launch(void* const* d_in, const int* in_sizes, int n_in,
                              void* d_out, int out_size, void* d_ws, size_t ws_size,
                              hipStream_t stream) {
    const float* X = (const float*)d_in[0];
    const float* Y = (const float*)d_in[1];
    float* out = (float*)d_out;

    if (ws_size >= 2 * NPTS * sizeof(unsigned)) {
        unsigned* wsmin = (unsigned*)d_ws;
        init_min_kernel<<<(2 * NPTS + THREADS - 1) / THREADS, THREADS, 0, stream>>>(
            wsmin, 2 * NPTS);
        pair_min_kernel<<<2 * BLOCKS_PER_DIR, THREADS, 0, stream>>>(
            X, Y, wsmin, wsmin + NPTS);
        finalize_kernel<<<1, THREADS, 0, stream>>>(wsmin, out, 2 * NPTS);
    } else {
        init_scalar_kernel<<<1, 64, 0, stream>>>((unsigned*)d_out);
        hausdorff_simple_kernel<<<2 * (NPTS / THREADS), THREADS, 0, stream>>>(
            X, Y, (unsigned*)d_out);
        sqrt_inplace_kernel<<<1, 64, 0, stream>>>(out);
    }
}

// Round 2
// 42.349 us; speedup vs baseline: 1.4038x; 1.4038x over previous
//
#include <hip/hip_runtime.h>
#include <math.h>

// Hausdorff distance, X[8192,3] vs Y[8192,3] fp32.
// d2(i,j) = |a_i|^2 - 2*(a_i . b_j - |b_j|^2/2)  -> 3 FMA + 1 max per pair.
// Per (dir, rowchunk, colchunk) block: partial min-d2 per row -> ws.
// Then: min over colchunks, max over rows, sqrt.

constexpr int NPTS = 8192;
constexpr int T = 256;          // threads per block
constexpr int R = 8;            // rows per thread
constexpr int ROWS_PB = T * R;  // 2048 rows per block
constexpr int RG = NPTS / ROWS_PB;  // 4 row groups per direction

template <int CG>
__global__ __launch_bounds__(T) void pair_partial_kernel(
        const float* __restrict__ X, const float* __restrict__ Y,
        float* __restrict__ partial) {
    constexpr int COLS = NPTS / CG;  // B points per block
    int b = blockIdx.x;
    int dir = b / (RG * CG);
    int rem = b - dir * (RG * CG);
    int rg = rem / CG;
    int cg = rem - rg * CG;
    const float* A = dir ? Y : X;
    const float* B = dir ? X : Y;

    int t = threadIdx.x;
    int r0 = rg * ROWS_PB + t;

    // Issue A-row loads first so their latency hides under staging.
    float ax[R], ay[R], az[R], na[R], mt[R];
#pragma unroll
    for (int k = 0; k < R; ++k) {
        int row = r0 + k * T;
        ax[k] = A[row * 3 + 0];
        ay[k] = A[row * 3 + 1];
        az[k] = A[row * 3 + 2];
    }

    // Stage this block's B chunk as (x, y, z, -0.5*|b|^2) float4s.
    __shared__ float4 Bs[COLS];
    for (int i = t; i < COLS; i += T) {
        int j = cg * COLS + i;
        float bx = B[j * 3 + 0], by = B[j * 3 + 1], bz = B[j * 3 + 2];
        float c = -0.5f * fmaf(bx, bx, fmaf(by, by, bz * bz));
        Bs[i] = make_float4(bx, by, bz, c);
    }

#pragma unroll
    for (int k = 0; k < R; ++k) {
        na[k] = fmaf(ax[k], ax[k], fmaf(ay[k], ay[k], az[k] * az[k]));
        mt[k] = -__builtin_inff();
    }
    __syncthreads();

#pragma unroll 4
    for (int j = 0; j < COLS; ++j) {
        float4 p = Bs[j];  // wave-uniform address -> ds_read_b128 broadcast
#pragma unroll
        for (int k = 0; k < R; ++k) {
            float tt = fmaf(ax[k], p.x, fmaf(ay[k], p.y, fmaf(az[k], p.z, p.w)));
            mt[k] = fmaxf(mt[k], tt);
        }
    }

    // partial d2-min for this col chunk; coalesced stores
    float* op = partial + (size_t)(dir * CG + cg) * NPTS + rg * ROWS_PB + t;
#pragma unroll
    for (int k = 0; k < R; ++k) op[k * T] = fmaf(-2.f, mt[k], na[k]);
}

__global__ __launch_bounds__(T) void reduce_kernel(
        const float* __restrict__ partial, float* __restrict__ blockmax, int cgn) {
    int rid = blockIdx.x * T + threadIdx.x;  // 0..16383
    int dir = rid >> 13;
    int row = rid & (NPTS - 1);
    const float* p = partial + (size_t)dir * cgn * NPTS + row;
    float m = __builtin_inff();
    for (int cg = 0; cg < cgn; ++cg) m = fminf(m, p[(size_t)cg * NPTS]);
    m = fmaxf(m, 0.f);  // dot-form can go slightly negative
    for (int o = 32; o > 0; o >>= 1) m = fmaxf(m, __shfl_down(m, o));
    __shared__ float wm[T / 64];
    if ((threadIdx.x & 63) == 0) wm[threadIdx.x >> 6] = m;
    __syncthreads();
    if (threadIdx.x == 0) {
        float mm = wm[0];
        for (int w = 1; w < T / 64; ++w) mm = fmaxf(mm, wm[w]);
        blockmax[blockIdx.x] = mm;
    }
}

__global__ void final_kernel(const float* __restrict__ blockmax,
                             float* __restrict__ out, int n) {
    float m = blockmax[threadIdx.x < n ? threadIdx.x : 0];
    for (int o = 32; o > 0; o >>= 1) m = fmaxf(m, __shfl_down(m, o));
    if (threadIdx.x == 0) out[0] = sqrtf(m);
}

// ---------- fallback path (small ws): round-1 atomic version ----------

constexpr int SEG_J = 512;
constexpr int SEGS = NPTS / SEG_J;

__global__ void init_min_kernel(unsigned* wsmin, int n) {
    int i = blockIdx.x * blockDim.x + threadIdx.x;
    if (i < n) wsmin[i] = 0x7F800000u;
}

__global__ __launch_bounds__(T) void pair_min_kernel(
        const float* __restrict__ X, const float* __restrict__ Y,
        unsigned* __restrict__ minXY, unsigned* __restrict__ minYX) {
    constexpr int BLOCKS_PER_DIR = RG * SEGS;
    int b = blockIdx.x;
    int dir = b / BLOCKS_PER_DIR;
    int rem = b - dir * BLOCKS_PER_DIR;
    int rg = rem / SEGS;
    int seg = rem - rg * SEGS;
    const float* A = dir ? Y : X;
    const float* B = dir ? X : Y;
    unsigned* omin = dir ? minYX : minXY;

    __shared__ float Bs[SEG_J * 3];
    int t = threadIdx.x;
    const float* Bseg = B + seg * SEG_J * 3;
    for (int i = t; i < SEG_J * 3; i += T) Bs[i] = Bseg[i];

    int r0 = rg * ROWS_PB + t;
    float ax[R], ay[R], az[R], m[R];
#pragma unroll
    for (int r = 0; r < R; ++r) {
        int row = r0 + r * T;
        ax[r] = A[row * 3 + 0];
        ay[r] = A[row * 3 + 1];
        az[r] = A[row * 3 + 2];
        m[r] = __builtin_inff();
    }
    __syncthreads();

#pragma unroll 2
    for (int j = 0; j < SEG_J; ++j) {
        float bx = Bs[3 * j + 0], by = Bs[3 * j + 1], bz = Bs[3 * j + 2];
#pragma unroll
        for (int r = 0; r < R; ++r) {
            float dx = ax[r] - bx, dy = ay[r] - by, dz = az[r] - bz;
            m[r] = fminf(m[r], fmaf(dx, dx, fmaf(dy, dy, dz * dz)));
        }
    }
#pragma unroll
    for (int r = 0; r < R; ++r)
        atomicMin(&omin[r0 + r * T], __float_as_uint(m[r]));
}

__global__ __launch_bounds__(T) void finalize_min_kernel(
        const unsigned* __restrict__ wsmin, float* __restrict__ out, int n) {
    int t = threadIdx.x;
    float mx = 0.f;
    for (int i = t; i < n; i += T) mx = fmaxf(mx, __uint_as_float(wsmin[i]));
    for (int o = 32; o > 0; o >>= 1) mx = fmaxf(mx, __shfl_down(mx, o));
    __shared__ float wmax[T / 64];
    if ((t & 63) == 0) wmax[t >> 6] = mx;
    __syncthreads();
    if (t == 0) {
        float mm = wmax[0];
        for (int w = 1; w < T / 64; ++w) mm = fmaxf(mm, wmax[w]);
        out[0] = sqrtf(mm);
    }
}

extern "C" void kernel_launch(void* const* d_in, const int* in_sizes, int n_in,
                              void* d_out, int out_size, void* d_ws, size_t ws_size,
                              hipStream_t stream) {
    const float* X = (const float*)d_in[0];
    const float* Y = (const float*)d_in[1];
    float* out = (float*)d_out;

    const size_t need128 = (size_t)(2 * 128 * NPTS + 64) * sizeof(float);
    const size_t need64  = (size_t)(2 * 64  * NPTS + 64) * sizeof(float);

    if (ws_size >= need128) {
        constexpr int CG = 128;
        float* partial = (float*)d_ws;
        float* blockmax = partial + 2 * CG * NPTS;
        pair_partial_kernel<CG><<<2 * RG * CG, T, 0, stream>>>(X, Y, partial);
        reduce_kernel<<<2 * NPTS / T, T, 0, stream>>>(partial, blockmax, CG);
        final_kernel<<<1, 64, 0, stream>>>(blockmax, out, 2 * NPTS / T);
    } else if (ws_size >= need64) {
        constexpr int CG = 64;
        float* partial = (float*)d_ws;
        float* blockmax = partial + 2 * CG * NPTS;
        pair_partial_kernel<CG><<<2 * RG * CG, T, 0, stream>>>(X, Y, partial);
        reduce_kernel<<<2 * NPTS / T, T, 0, stream>>>(partial, blockmax, CG);
        final_kernel<<<1, 64, 0, stream>>>(blockmax, out, 2 * NPTS / T);
    } else if (ws_size >= 2 * NPTS * sizeof(unsigned)) {
        unsigned* wsmin = (unsigned*)d_ws;
        init_min_kernel<<<(2 * NPTS + T - 1) / T, T, 0, stream>>>(wsmin, 2 * NPTS);
        pair_min_kernel<<<2 * RG * SEGS, T, 0, stream>>>(X, Y, wsmin, wsmin + NPTS);
        finalize_min_kernel<<<1, T, 0, stream>>>(wsmin, out, 2 * NPTS);
    }
}